// Round 4
// baseline (587.313 us; speedup 1.0000x reference)
//
#include <hip/hip_runtime.h>
#include <hip/hip_cooperative_groups.h>
#include <math.h>

namespace cg = cooperative_groups;

#define NPTS 16384
#define KNB  16
#define D    512
#define NBLK 256
#define NTHR 256
#define TOT  (NBLK * NTHR)  // 65536
#define ZSTR 4608           // 9*512

// ---------------------------------------------------------------------------
// Closed-form restructure (verified rounds 1-3, absmax 0.0625). With
// S = gather-mean, R = Wres^T + I, M = W2c*W1, f' = Cb + S^2 f M^T + f R,
// f0 = 0:
//   f4 = Cb*(I+R+R^2+R^3)
//      + S^2Cb*(M' + RM' + R^2M' + M'R + RM'R + M'RR)    [M' = M^T]
//      + S^4Cb*(M'M' + RM'M' + M'RM' + M'M'R)
//      + S^6Cb*(M'M'M')
// Cb = [gm, S gm, 1]*Z^T, Z = [P|Q|btot]; everything collapses to weight-space
// words z*word (z [9,512]) and a final [N,33]x[33,512] product.
// This round: single cooperative kernel, 5 grid.sync() phases. Even powers of
// S via direct 2-hop gathers (256 composed neighbors) to halve barrier depth.
// ---------------------------------------------------------------------------

struct Job { int src, mat, dst; };
__device__ __constant__ Job g_jobs[14] = {
  {0,1,1},{0,0,4},                                                      // d1
  {1,1,2},{1,0,5},{4,1,6},{4,0,7},                                      // d2
  {2,1,3},{2,0,8},{5,1,9},{5,0,11},{6,1,10},{6,0,12},{7,1,13},{7,0,14}  // d3
};
// slots: 0 z | 1 zR | 2 zR2 | 3 zR3 | 4 zM | 5 zRM | 6 zMR | 7 zMM |
//        8 zR2M | 9 zRMR | 10 zMRR | 11 zRMM | 12 zMRM | 13 zMMR | 14 zMMM
__device__ __constant__ int g_eslots[4][6] = {
  {0, 1, 2, 3, -1, -1},
  {4, 5, 8, 6, 9, 10},
  {7, 11, 12, 13, -1, -1},
  {14, -1, -1, -1, -1, -1}};

__device__ __forceinline__ int knn_at(const int* __restrict__ raw, bool is64,
                                      int e) {
  return is64 ? raw[2 * e] : raw[e];
}

// chain helper: outputs for jobs [jbase, jbase+jcnt) strided over 16384 thr
__device__ __forceinline__ void chain_work(int rel, int jbase, int jcnt,
                                           float* __restrict__ zbuf,
                                           const float* __restrict__ Rm,
                                           const float* __restrict__ Mt) {
  for (int u = rel; u < jcnt * 9 * 512; u += 16384) {
    int col = u & 511;
    int rowid = u >> 9;
    int c = rowid % 9, job = rowid / 9;
    Job jb = g_jobs[jbase + job];
    const float* src = zbuf + jb.src * ZSTR + c * D;  // wave-broadcast
    const float* B = jb.mat ? Rm : Mt;                // coalesced in col
    double a0 = 0, a1 = 0, a2 = 0, a3 = 0;
    for (int i = 0; i < D; i += 4) {
      a0 += (double)src[i + 0] * (double)B[(size_t)(i + 0) * D + col];
      a1 += (double)src[i + 1] * (double)B[(size_t)(i + 1) * D + col];
      a2 += (double)src[i + 2] * (double)B[(size_t)(i + 2) * D + col];
      a3 += (double)src[i + 3] * (double)B[(size_t)(i + 3) * D + col];
    }
    zbuf[jb.dst * ZSTR + c * D + col] = (float)((a0 + a1) + (a2 + a3));
  }
}

// 1-hop: out[n] = mean_k in[knn[n,k]]; one thread per point (rel < 16384)
__device__ __forceinline__ void onehop(int n, const int* __restrict__ raw,
                                       bool is64, const float4* __restrict__ in,
                                       float4* __restrict__ out) {
  float ax = 0.f, ay = 0.f, az = 0.f, aw = 0.f;
#pragma unroll
  for (int k = 0; k < KNB; ++k) {
    float4 g = in[knn_at(raw, is64, n * KNB + k)];
    ax += g.x; ay += g.y; az += g.z; aw += g.w;
  }
  const float r = 1.f / 16.f;
  out[n] = make_float4(ax * r, ay * r, az * r, aw * r);
}

// 2-hop: out[n] = mean over 256 composed neighbors; 2 threads per point
__device__ __forceinline__ void twohop(int t, const int* __restrict__ raw,
                                       bool is64, const float4* __restrict__ in,
                                       float4* __restrict__ out) {
  int n = t >> 1, half = t & 1;
  float ax = 0.f, ay = 0.f, az = 0.f, aw = 0.f;
#pragma unroll
  for (int a = 0; a < 8; ++a) {
    int ia = knn_at(raw, is64, n * KNB + half * 8 + a);
#pragma unroll
    for (int b = 0; b < KNB; ++b) {
      float4 g = in[knn_at(raw, is64, ia * KNB + b)];
      ax += g.x; ay += g.y; az += g.z; aw += g.w;
    }
  }
  ax += __shfl_xor(ax, 1, 64); ay += __shfl_xor(ay, 1, 64);
  az += __shfl_xor(az, 1, 64); aw += __shfl_xor(aw, 1, 64);
  if (half == 0) {
    const float r = 1.f / 256.f;
    out[n] = make_float4(ax * r, ay * r, az * r, aw * r);
  }
}

__global__ __launch_bounds__(NTHR) void fused_kernel(
    const float* __restrict__ pts, const int* __restrict__ raw,
    const float* __restrict__ w_mlp1, const float* __restrict__ b_mlp1,
    const float* __restrict__ w_lfa1, const float* __restrict__ b_lfa1,
    const float* __restrict__ w_lfa2, const float* __restrict__ b_lfa2,
    const float* __restrict__ w_mlp2, const float* __restrict__ b_mlp2,
    const float* __restrict__ w_res, const float* __restrict__ b_res,
    float4* __restrict__ sbase, float* __restrict__ zbuf,
    float* __restrict__ Ecat, float* __restrict__ Mt, float* __restrict__ Rm,
    float* __restrict__ outp) {
  cg::grid_group grid = cg::this_grid();
  const int t = blockIdx.x * NTHR + threadIdx.x;
  // knn dtype probe (int64 => odd words are zero high halves); uniform branch
  const bool is64 = (raw[1] == 0) && (raw[3] == 0) && (raw[5] == 0) &&
                    (raw[7] == 0);

  // ---------------- P0: geo | pq (z) | Mt | Rm ----------------
  if (t < NPTS) {
    int n = t;
    float px = pts[n * 3 + 0], py = pts[n * 3 + 1], pz = pts[n * 3 + 2];
    float ax = 0.f, ay = 0.f, az = 0.f, an = 0.f;
#pragma unroll
    for (int k = 0; k < KNB; ++k) {
      int idx = knn_at(raw, is64, n * KNB + k);
      float dx = px - pts[idx * 3 + 0];
      float dy = py - pts[idx * 3 + 1];
      float dz = pz - pts[idx * 3 + 2];
      ax += dx; ay += dy; az += dz;
      an += sqrtf(dx * dx + dy * dy + dz * dz);
    }
    const float r = 1.f / 16.f;
    sbase[n] = make_float4(ax * r, ay * r, az * r, an * r);
  } else if (t < NPTS + 32768) {
    // pq: one wave (64 lanes) per output column j; fp64 accumulate
    int rel = t - NPTS;
    int j = rel >> 6, lane = rel & 63;
    const float* wrow = w_mlp2 + (size_t)j * D;
    double acc[9];
#pragma unroll
    for (int u = 0; u < 9; ++u) acc[u] = 0.0;
#pragma unroll
    for (int it = 0; it < 8; ++it) {
      int i = lane + 64 * it;  // segment is uniform per it
      double w = wrow[i];
      if (i < 256) {
        acc[0] += w * w_lfa2[i * 4 + 0]; acc[1] += w * w_lfa2[i * 4 + 1];
        acc[2] += w * w_lfa2[i * 4 + 2]; acc[3] += w * w_lfa2[i * 4 + 3];
        acc[8] += w * b_lfa2[i];
      } else if (i < 384) {
        int q = i - 256;
        acc[4] += w * w_lfa1[q * 4 + 0]; acc[5] += w * w_lfa1[q * 4 + 1];
        acc[6] += w * w_lfa1[q * 4 + 2]; acc[7] += w * w_lfa1[q * 4 + 3];
        acc[8] += w * b_lfa1[q];
      } else {
        acc[8] += w * b_mlp1[i - 384];
      }
    }
#pragma unroll
    for (int u = 0; u < 9; ++u) {
      double v = acc[u];
#pragma unroll
      for (int o = 32; o > 0; o >>= 1) v += __shfl_down(v, o, 64);
      if (lane == 0) {
        if (u == 8) v += (double)b_mlp2[j] + (double)b_res[j];
        zbuf[u * D + j] = (float)v;
      }
    }
  }
  // Mt[a*D+b] = sum_{i<128} w_mlp2[b][384+i]*w_mlp1[i][a]  (= M^T[a][b])
  for (int u = t; u < D * D; u += TOT) {
    int a = u & 511, b = u >> 9;                       // coalesced in a
    const float* wrow = w_mlp2 + (size_t)b * D + 384;  // wave-broadcast
    double s = 0.0;
#pragma unroll 4
    for (int i = 0; i < 128; ++i)
      s += (double)wrow[i] * (double)w_mlp1[(size_t)i * D + a];
    Mt[(size_t)a * D + b] = (float)s;
  }
  // Rm[i*D+j] = w_res[j][i] + (i==j)
  for (int u = t; u < D * D; u += TOT) {
    int i = u & 511, j = u >> 9;  // coalesced read of w_res row j
    Rm[(size_t)i * D + j] = w_res[(size_t)j * D + i] + ((i == j) ? 1.0f : 0.0f);
  }
  grid.sync();

  // ------- P1..P3: {s_{2p+2} 2-hop, s_{2p+1} 1-hop, chain depth p+1} -------
  const int jb_base[3] = {0, 2, 6};
  const int jb_cnt[3]  = {2, 4, 8};
  for (int p = 0; p < 3; ++p) {
    int kin = 2 * p;
    if (t < 32768) {
      twohop(t, raw, is64, sbase + (size_t)kin * NPTS,
             sbase + (size_t)(kin + 2) * NPTS);
    } else if (t < 49152) {
      onehop(t - 32768, raw, is64, sbase + (size_t)kin * NPTS,
             sbase + (size_t)(kin + 1) * NPTS);
    } else {
      chain_work(t - 49152, jb_base[p], jb_cnt[p], zbuf, Rm, Mt);
    }
    grid.sync();
  }

  // ---------------- P4: s7 = S s6 | combine -> Ecat ----------------
  if (t >= 32768 && t < 49152) {
    onehop(t - 32768, raw, is64, sbase + (size_t)6 * NPTS,
           sbase + (size_t)7 * NPTS);
  }
  if (t < 33 * 512) {
    int r = t >> 9, j = t & 511;
    float s = 0.f;
    if (r < 32) {
      int ci = r >> 3, c = r & 7;
#pragma unroll
      for (int u = 0; u < 6; ++u) {
        int sl = g_eslots[ci][u];
        if (sl >= 0) s += zbuf[sl * ZSTR + c * D + j];
      }
    } else {
#pragma unroll
      for (int sl = 0; sl < 15; ++sl) s += zbuf[sl * ZSTR + 8 * D + j];
    }
    Ecat[r * D + j] = s;
  }
  grid.sync();

  // ---------------- P5: out[n][j] = [s0..s7,1][n] x Ecat ----------------
  for (int u = t; u < NPTS * 128; u += TOT) {
    int n = u >> 7, c4 = u & 127;
    int col = c4 * 4;
    float4 acc = *(const float4*)(Ecat + 32 * D + col);  // bias row
#pragma unroll
    for (int k = 0; k < 8; ++k) {
      float4 s = sbase[(size_t)k * NPTS + n];
      float4 e0 = *(const float4*)(Ecat + (4 * k + 0) * D + col);
      float4 e1 = *(const float4*)(Ecat + (4 * k + 1) * D + col);
      float4 e2 = *(const float4*)(Ecat + (4 * k + 2) * D + col);
      float4 e3 = *(const float4*)(Ecat + (4 * k + 3) * D + col);
      acc.x += s.x * e0.x + s.y * e1.x + s.z * e2.x + s.w * e3.x;
      acc.y += s.x * e0.y + s.y * e1.y + s.z * e2.y + s.w * e3.y;
      acc.z += s.x * e0.z + s.y * e1.z + s.z * e2.z + s.w * e3.z;
      acc.w += s.x * e0.w + s.y * e1.w + s.z * e2.w + s.w * e3.w;
    }
    *(float4*)(outp + (size_t)n * D + col) = acc;
  }
}

extern "C" void kernel_launch(void* const* d_in, const int* in_sizes, int n_in,
                              void* d_out, int out_size, void* d_ws,
                              size_t ws_size, hipStream_t stream) {
  const float* inputs = (const float*)d_in[0];
  const int* knn_raw  = (const int*)d_in[1];
  const float* w_mlp1 = (const float*)d_in[2];
  const float* b_mlp1 = (const float*)d_in[3];
  const float* w_lfa1 = (const float*)d_in[4];
  const float* b_lfa1 = (const float*)d_in[5];
  const float* w_lfa2 = (const float*)d_in[6];
  const float* b_lfa2 = (const float*)d_in[7];
  const float* w_mlp2 = (const float*)d_in[8];
  const float* b_mlp2 = (const float*)d_in[9];
  const float* w_res  = (const float*)d_in[10];
  const float* b_res  = (const float*)d_in[11];
  float* out = (float*)d_out;

  // workspace layout (floats): ~4.5 MB
  float*  ws    = (float*)d_ws;
  float4* sbase = (float4*)(ws + 0);   // 8 * 16384 float4 = 524288 floats
  float*  zbuf  = ws + 524288;         // 15 * 4608 = 69120
  float*  Ecat  = ws + 593408;         // 33 * 512  = 16896
  float*  Mt    = ws + 610304;         // 262144
  float*  Rm    = ws + 872448;         // 262144

  void* args[] = {&inputs, &knn_raw, &w_mlp1, &b_mlp1, &w_lfa1, &b_lfa1,
                  &w_lfa2, &b_lfa2, &w_mlp2, &b_mlp2, &w_res, &b_res,
                  &sbase, &zbuf, &Ecat, &Mt, &Rm, &out};
  hipLaunchCooperativeKernel((const void*)fused_kernel, dim3(NBLK), dim3(NTHR),
                             args, 0, stream);
}

// Round 5
// 550.169 us; speedup vs baseline: 1.0675x; 1.0675x over previous
//
#include <hip/hip_runtime.h>
#include <hip/hip_cooperative_groups.h>
#include <math.h>

namespace cg = cooperative_groups;

#define NPTS 16384
#define KNB  16
#define D    512
#define NBLK 256
#define NTHR 1024
#define TOT  (NBLK * NTHR)  // 262144 == D*D
#define ZSTR 4608           // 9*512

// ---------------------------------------------------------------------------
// Closed-form restructure (verified rounds 1-4, absmax 0.0625). With
// S = gather-mean, R = Wres^T + I, M = W2c*W1, f' = Cb + S^2 f M^T + f R,
// f0 = 0:
//   f4 = Cb*(I+R+R^2+R^3)
//      + S^2Cb*(M' + RM' + R^2M' + M'R + RM'R + M'RR)    [M' = M^T]
//      + S^4Cb*(M'M' + RM'M' + M'RM' + M'M'R)
//      + S^6Cb*(M'M'M')
// Single cooperative kernel, 5 grid.sync() phases. Round-5 fixes round-4's
// TLP starvation: 1024-thr blocks (16 waves/CU), K-split x4 chain + LDS
// reduce, register-hoisted final GEMM.
// ---------------------------------------------------------------------------

struct Job { int src, mat, dst; };
__device__ __constant__ Job g_jobs[14] = {
  {0,1,1},{0,0,4},                                                      // d1
  {1,1,2},{1,0,5},{4,1,6},{4,0,7},                                      // d2
  {2,1,3},{2,0,8},{5,1,9},{5,0,11},{6,1,10},{6,0,12},{7,1,13},{7,0,14}  // d3
};
// slots: 0 z | 1 zR | 2 zR2 | 3 zR3 | 4 zM | 5 zRM | 6 zMR | 7 zMM |
//        8 zR2M | 9 zRMR | 10 zMRR | 11 zRMM | 12 zMRM | 13 zMMR | 14 zMMM
__device__ __constant__ int g_eslots[4][6] = {
  {0, 1, 2, 3, -1, -1},
  {4, 5, 8, 6, 9, 10},
  {7, 11, 12, 13, -1, -1},
  {14, -1, -1, -1, -1, -1}};

__device__ __forceinline__ int knn_at(const int* __restrict__ raw, bool is64,
                                      int e) {
  return is64 ? raw[2 * e] : raw[e];
}

// 1-hop: out[n] = mean_k in[knn[n,k]]
__device__ __forceinline__ void onehop(int n, const int* __restrict__ raw,
                                       bool is64, const float4* __restrict__ in,
                                       float4* __restrict__ out) {
  float ax = 0.f, ay = 0.f, az = 0.f, aw = 0.f;
#pragma unroll
  for (int k = 0; k < KNB; ++k) {
    float4 g = in[knn_at(raw, is64, n * KNB + k)];
    ax += g.x; ay += g.y; az += g.z; aw += g.w;
  }
  const float r = 1.f / 16.f;
  out[n] = make_float4(ax * r, ay * r, az * r, aw * r);
}

__global__ __launch_bounds__(NTHR) void fused_kernel(
    const float* __restrict__ pts, const int* __restrict__ raw,
    const float* __restrict__ w_mlp1, const float* __restrict__ b_mlp1,
    const float* __restrict__ w_lfa1, const float* __restrict__ b_lfa1,
    const float* __restrict__ w_lfa2, const float* __restrict__ b_lfa2,
    const float* __restrict__ w_mlp2, const float* __restrict__ b_mlp2,
    const float* __restrict__ w_res, const float* __restrict__ b_res,
    float4* __restrict__ sbase, float* __restrict__ zbuf,
    float* __restrict__ Ecat, float* __restrict__ Mt, float* __restrict__ Rm,
    float* __restrict__ outp) {
  cg::grid_group grid = cg::this_grid();
  const int tid = threadIdx.x;
  const int t = blockIdx.x * NTHR + tid;
  const bool is64 = (raw[1] == 0) && (raw[3] == 0) && (raw[5] == 0) &&
                    (raw[7] == 0);

  __shared__ double pred[4][256];

  // ---------------- P0: geo | pq (z) | Mt | Rm ----------------
  if (t < NPTS) {
    int n = t;
    float px = pts[n * 3 + 0], py = pts[n * 3 + 1], pz = pts[n * 3 + 2];
    float ax = 0.f, ay = 0.f, az = 0.f, an = 0.f;
#pragma unroll
    for (int k = 0; k < KNB; ++k) {
      int idx = knn_at(raw, is64, n * KNB + k);
      float dx = px - pts[idx * 3 + 0];
      float dy = py - pts[idx * 3 + 1];
      float dz = pz - pts[idx * 3 + 2];
      ax += dx; ay += dy; az += dz;
      an += sqrtf(dx * dx + dy * dy + dz * dz);
    }
    const float r = 1.f / 16.f;
    sbase[n] = make_float4(ax * r, ay * r, az * r, an * r);
  } else if (t < NPTS + 32768) {
    // pq: one wave per output column j; fp64 accumulate
    int rel = t - NPTS;
    int j = rel >> 6, lane = rel & 63;
    const float* wrow = w_mlp2 + (size_t)j * D;
    double acc[9];
#pragma unroll
    for (int u = 0; u < 9; ++u) acc[u] = 0.0;
#pragma unroll
    for (int it = 0; it < 8; ++it) {
      int i = lane + 64 * it;
      double w = wrow[i];
      if (i < 256) {
        acc[0] += w * w_lfa2[i * 4 + 0]; acc[1] += w * w_lfa2[i * 4 + 1];
        acc[2] += w * w_lfa2[i * 4 + 2]; acc[3] += w * w_lfa2[i * 4 + 3];
        acc[8] += w * b_lfa2[i];
      } else if (i < 384) {
        int q = i - 256;
        acc[4] += w * w_lfa1[q * 4 + 0]; acc[5] += w * w_lfa1[q * 4 + 1];
        acc[6] += w * w_lfa1[q * 4 + 2]; acc[7] += w * w_lfa1[q * 4 + 3];
        acc[8] += w * b_lfa1[q];
      } else {
        acc[8] += w * b_mlp1[i - 384];
      }
    }
#pragma unroll
    for (int u = 0; u < 9; ++u) {
      double v = acc[u];
#pragma unroll
      for (int o = 32; o > 0; o >>= 1) v += __shfl_down(v, o, 64);
      if (lane == 0) {
        if (u == 8) v += (double)b_mlp2[j] + (double)b_res[j];
        zbuf[u * D + j] = (float)v;
      }
    }
  }
  {  // Mt: exactly one output per thread (TOT == D*D)
    int a = t & 511, b = t >> 9;                       // coalesced in a
    const float* wrow = w_mlp2 + (size_t)b * D + 384;  // wave-broadcast (b uni)
    double s0 = 0.0, s1 = 0.0, s2 = 0.0, s3 = 0.0;
#pragma unroll 8
    for (int i = 0; i < 128; i += 4) {
      s0 += (double)wrow[i + 0] * (double)w_mlp1[(size_t)(i + 0) * D + a];
      s1 += (double)wrow[i + 1] * (double)w_mlp1[(size_t)(i + 1) * D + a];
      s2 += (double)wrow[i + 2] * (double)w_mlp1[(size_t)(i + 2) * D + a];
      s3 += (double)wrow[i + 3] * (double)w_mlp1[(size_t)(i + 3) * D + a];
    }
    Mt[(size_t)a * D + b] = (float)((s0 + s1) + (s2 + s3));
  }
  {  // Rm[i*D+j] = w_res[j][i] + (i==j); coalesced read, L2-merged scatter wr
    int i = t & 511, j = t >> 9;
    Rm[(size_t)i * D + j] = w_res[(size_t)j * D + i] + ((i == j) ? 1.0f : 0.0f);
  }
  grid.sync();

  // ---- P1..P3: {s_{2p+2} 2-hop, s_{2p+1} 1-hop, chain depth p+1} ----
  // blocks 0..63 twohop | 64..79 onehop | 80..255 chain (block-aligned)
  const int jb_base[3] = {0, 2, 6};
  const int jb_cnt[3]  = {2, 4, 8};
  for (int p = 0; p < 3; ++p) {
    const float4* sin = sbase + (size_t)(2 * p) * NPTS;
    if (t < 65536) {
      // twohop: 4 threads/point, 64 gathers each, shfl-reduce across 4 lanes
      int n = t >> 2, q = t & 3;
      float ax = 0.f, ay = 0.f, az = 0.f, aw = 0.f;
#pragma unroll
      for (int a = 0; a < 4; ++a) {
        int ia = knn_at(raw, is64, n * KNB + q * 4 + a);
#pragma unroll
        for (int b = 0; b < KNB; ++b) {
          float4 g = sin[knn_at(raw, is64, ia * KNB + b)];
          ax += g.x; ay += g.y; az += g.z; aw += g.w;
        }
      }
      ax += __shfl_xor(ax, 1, 64); ay += __shfl_xor(ay, 1, 64);
      az += __shfl_xor(az, 1, 64); aw += __shfl_xor(aw, 1, 64);
      ax += __shfl_xor(ax, 2, 64); ay += __shfl_xor(ay, 2, 64);
      az += __shfl_xor(az, 2, 64); aw += __shfl_xor(aw, 2, 64);
      if (q == 0) {
        const float r = 1.f / 256.f;
        sbase[(size_t)(2 * p + 2) * NPTS + n] =
            make_float4(ax * r, ay * r, az * r, aw * r);
      }
    } else if (t < 81920) {
      onehop(t - 65536, raw, is64, sin, sbase + (size_t)(2 * p + 1) * NPTS);
    } else {
      // chain with K-split x4: block handles 256 outputs x 4 K-chunks
      int chunk = tid >> 8, ol = tid & 255;
      int total = jb_cnt[p] * 9 * 512;
      int out = (blockIdx.x - 80) * 256 + ol;
      double acc = 0.0;
      int col = out & 511, row = out >> 9;
      int c = row % 9, job = row / 9;
      if (out < total) {
        Job jb = g_jobs[jb_base[p] + job];
        const float* sp = zbuf + jb.src * ZSTR + c * D + chunk * 128;
        const float* B =
            (jb.mat ? Rm : Mt) + (size_t)(chunk * 128) * D + col;
        double a0 = 0, a1 = 0, a2 = 0, a3 = 0;
        for (int i = 0; i < 128; i += 4) {
          a0 += (double)sp[i + 0] * (double)B[(size_t)(i + 0) * D];
          a1 += (double)sp[i + 1] * (double)B[(size_t)(i + 1) * D];
          a2 += (double)sp[i + 2] * (double)B[(size_t)(i + 2) * D];
          a3 += (double)sp[i + 3] * (double)B[(size_t)(i + 3) * D];
        }
        acc = (a0 + a1) + (a2 + a3);
      }
      pred[chunk][ol] = acc;
      __syncthreads();
      if (tid < 256 && out < total) {
        double s = pred[0][ol] + pred[1][ol] + pred[2][ol] + pred[3][ol];
        Job jb = g_jobs[jb_base[p] + job];
        zbuf[jb.dst * ZSTR + c * D + col] = (float)s;
      }
      __syncthreads();  // protect pred for next p
    }
    grid.sync();
  }

  // ---------------- P4: s7 = S s6 | combine -> Ecat ----------------
  if (t < NPTS) {
    onehop(t, raw, is64, sbase + (size_t)6 * NPTS,
           sbase + (size_t)7 * NPTS);
  } else if (t < NPTS + 33 * 512) {
    int rel = t - NPTS;
    int r = rel >> 9, j = rel & 511;
    float s = 0.f;
    if (r < 32) {
      int ci = r >> 3, c = r & 7;
#pragma unroll
      for (int u = 0; u < 6; ++u) {
        int sl = g_eslots[ci][u];
        if (sl >= 0) s += zbuf[sl * ZSTR + c * D + j];
      }
    } else {
#pragma unroll
      for (int sl = 0; sl < 15; ++sl) s += zbuf[sl * ZSTR + 8 * D + j];
    }
    Ecat[r * D + j] = s;
  }
  grid.sync();

  // ------- P5: out[n][:] = [s0..s7,1][n] x Ecat, hoisted-register form -----
  {
    int col2 = t & 255;       // this thread's float2 column (fixed)
    int g = t >> 8;           // n-group, wave-uniform (lanes live in col2 bits)
    float2 tab[33];
#pragma unroll
    for (int r = 0; r < 33; ++r)
      tab[r] = *(const float2*)(Ecat + r * D + col2 * 2);
    for (int it = 0; it < 16; ++it) {
      int n = g + it * 1024;
      float2 acc = tab[32];  // bias row
#pragma unroll
      for (int k = 0; k < 8; ++k) {
        float4 s = sbase[(size_t)k * NPTS + n];  // wave-broadcast
        float2 e0 = tab[4 * k + 0], e1 = tab[4 * k + 1];
        float2 e2 = tab[4 * k + 2], e3 = tab[4 * k + 3];
        acc.x += s.x * e0.x + s.y * e1.x + s.z * e2.x + s.w * e3.x;
        acc.y += s.x * e0.y + s.y * e1.y + s.z * e2.y + s.w * e3.y;
      }
      *(float2*)(outp + (size_t)n * D + col2 * 2) = acc;
    }
  }
}

extern "C" void kernel_launch(void* const* d_in, const int* in_sizes, int n_in,
                              void* d_out, int out_size, void* d_ws,
                              size_t ws_size, hipStream_t stream) {
  const float* inputs = (const float*)d_in[0];
  const int* knn_raw  = (const int*)d_in[1];
  const float* w_mlp1 = (const float*)d_in[2];
  const float* b_mlp1 = (const float*)d_in[3];
  const float* w_lfa1 = (const float*)d_in[4];
  const float* b_lfa1 = (const float*)d_in[5];
  const float* w_lfa2 = (const float*)d_in[6];
  const float* b_lfa2 = (const float*)d_in[7];
  const float* w_mlp2 = (const float*)d_in[8];
  const float* b_mlp2 = (const float*)d_in[9];
  const float* w_res  = (const float*)d_in[10];
  const float* b_res  = (const float*)d_in[11];
  float* out = (float*)d_out;

  // workspace layout (floats): ~4.5 MB
  float*  ws    = (float*)d_ws;
  float4* sbase = (float4*)(ws + 0);   // 8 * 16384 float4 = 524288 floats
  float*  zbuf  = ws + 524288;         // 15 * 4608 = 69120
  float*  Ecat  = ws + 593408;         // 33 * 512  = 16896
  float*  Mt    = ws + 610304;         // 262144
  float*  Rm    = ws + 872448;         // 262144

  void* args[] = {&inputs, &knn_raw, &w_mlp1, &b_mlp1, &w_lfa1, &b_lfa1,
                  &w_lfa2, &b_lfa2, &w_mlp2, &b_mlp2, &w_res, &b_res,
                  &sbase, &zbuf, &Ecat, &Mt, &Rm, &out};
  hipLaunchCooperativeKernel((const void*)fused_kernel, dim3(NBLK), dim3(NTHR),
                             args, 0, stream);
}

// Round 6
// 287.875 us; speedup vs baseline: 2.0402x; 1.9111x over previous
//
#include <hip/hip_runtime.h>
#include <math.h>

#define NPTS 16384
#define KNB  16
#define D    512

// ---------------------------------------------------------------------------
// Closed-form restructure (verified rounds 1-5, absmax 0.0625):
//   f4 = Cb*(I+R+R^2+R^3) + S^2Cb*(M'+RM'+R^2M'+M'R+RM'R+M'RR)
//      + S^4Cb*(M'M'+RM'M'+M'RM'+M'M'R) + S^6Cb*(M'M'M')
// Cb = [gm, S gm, 1]*Z^T (rank 9)  =>  out = [s0..s7,1] ([N,33]) x Ecat.
// Round 6: back to plain sequential launches (round-5 showed grid.sync's
// device-scope fences cost ~200MB of HBM refetch on non-coherent XCD L2s).
// 5 dispatches; weight words computed depth-free per block (recompute
// prefixes; redundancy is cheap L2 traffic), s-chain via 1-hop+2-hop pairs,
// s7 computed inline in the output kernel.
// ---------------------------------------------------------------------------

// word letter sequences (applied left-to-right to z), 1 = R, 0 = M'
__device__ __constant__ int g_wlen[14] = {1,1,2,2,2,2,3,3,3,3,3,3,3,3};
__device__ __constant__ int g_wseq[14][3] = {
  {1,-1,-1},{0,-1,-1},                                  // R, M
  {1,1,-1},{1,0,-1},{0,1,-1},{0,0,-1},                  // RR, RM, MR, MM
  {1,1,1},{1,1,0},{1,0,1},{1,0,0},                      // RRR, RRM, RMR, RMM
  {0,1,1},{0,1,0},{0,0,1},{0,0,0}};                     // MRR, MRM, MMR, MMM
// combine groups: Ecat row-block ci sums these words (+z for ci==0)
__device__ __constant__ int g_wgroups[4][6] = {
  {0, 2, 6, -1, -1, -1},       // E1: z + R + RR + RRR
  {1, 3, 7, 4, 8, 10},         // E2: M + RM + RRM + MR + RMR + MRR
  {5, 9, 11, 12, -1, -1},      // E3: MM + RMM + MRM + MMR
  {13, -1, -1, -1, -1, -1}};   // E4: MMM

__device__ __forceinline__ bool knn_is64(const int* __restrict__ raw) {
  // int64 little-endian => odd words are zero high halves; (1/16384)^4 FP risk
  return (raw[1] == 0) && (raw[3] == 0) && (raw[5] == 0) && (raw[7] == 0);
}
__device__ __forceinline__ int knn_at(const int* __restrict__ raw, bool is64,
                                      int e) {
  return is64 ? raw[2 * e] : raw[e];
}

// 1-hop gather-mean (1 thread/point)
__device__ __forceinline__ void onehop(int n, const int* __restrict__ raw,
                                       bool is64, const float4* __restrict__ in,
                                       float4* __restrict__ out) {
  float ax = 0.f, ay = 0.f, az = 0.f, aw = 0.f;
#pragma unroll
  for (int k = 0; k < KNB; ++k) {
    float4 g = in[knn_at(raw, is64, n * KNB + k)];
    ax += g.x; ay += g.y; az += g.z; aw += g.w;
  }
  const float r = 1.f / 16.f;
  out[n] = make_float4(ax * r, ay * r, az * r, aw * r);
}

// 2-hop gather-mean (4 threads/point, shfl-reduce)
__device__ __forceinline__ void twohop(int r, const int* __restrict__ raw,
                                       bool is64, const float4* __restrict__ in,
                                       float4* __restrict__ out) {
  int n = r >> 2, q = r & 3;
  float ax = 0.f, ay = 0.f, az = 0.f, aw = 0.f;
#pragma unroll
  for (int a = 0; a < 4; ++a) {
    int ia = knn_at(raw, is64, n * KNB + q * 4 + a);
#pragma unroll
    for (int b = 0; b < KNB; ++b) {
      float4 g = in[knn_at(raw, is64, ia * KNB + b)];
      ax += g.x; ay += g.y; az += g.z; aw += g.w;
    }
  }
  ax += __shfl_xor(ax, 1, 64); ay += __shfl_xor(ay, 1, 64);
  az += __shfl_xor(az, 1, 64); aw += __shfl_xor(aw, 1, 64);
  ax += __shfl_xor(ax, 2, 64); ay += __shfl_xor(ay, 2, 64);
  az += __shfl_xor(az, 2, 64); aw += __shfl_xor(aw, 2, 64);
  if (q == 0) {
    const float rr = 1.f / 256.f;
    out[n] = make_float4(ax * rr, ay * rr, az * rr, aw * rr);
  }
}

// ---- L0: geo | pq (z rows 0..8) | Mt | Rm.  1024 blocks x 256 thr. ----
__global__ __launch_bounds__(256) void prep_kernel(
    const float* __restrict__ pts, const int* __restrict__ raw,
    const float* __restrict__ w_mlp1, const float* __restrict__ b_mlp1,
    const float* __restrict__ w_lfa1, const float* __restrict__ b_lfa1,
    const float* __restrict__ w_lfa2, const float* __restrict__ b_lfa2,
    const float* __restrict__ w_mlp2, const float* __restrict__ b_mlp2,
    const float* __restrict__ w_res, const float* __restrict__ b_res,
    float4* __restrict__ sbase, float* __restrict__ zbuf,
    float* __restrict__ Mt, float* __restrict__ Rm) {
  const bool is64 = knn_is64(raw);
  const int t = blockIdx.x * 256 + threadIdx.x;  // < 262144 == D*D
  if (t < NPTS) {
    int n = t;
    float px = pts[n * 3 + 0], py = pts[n * 3 + 1], pz = pts[n * 3 + 2];
    float ax = 0.f, ay = 0.f, az = 0.f, an = 0.f;
#pragma unroll
    for (int k = 0; k < KNB; ++k) {
      int idx = knn_at(raw, is64, n * KNB + k);
      float dx = px - pts[idx * 3 + 0];
      float dy = py - pts[idx * 3 + 1];
      float dz = pz - pts[idx * 3 + 2];
      ax += dx; ay += dy; az += dz;
      an += sqrtf(dx * dx + dy * dy + dz * dz);
    }
    const float r = 1.f / 16.f;
    sbase[n] = make_float4(ax * r, ay * r, az * r, an * r);
  } else if (t < NPTS + 32768) {
    // pq: one wave per output column j; fp64 accumulate
    int rel = t - NPTS;
    int j = rel >> 6, lane = rel & 63;
    const float* wrow = w_mlp2 + (size_t)j * D;
    double acc[9];
#pragma unroll
    for (int u = 0; u < 9; ++u) acc[u] = 0.0;
#pragma unroll
    for (int it = 0; it < 8; ++it) {
      int i = lane + 64 * it;
      double w = wrow[i];
      if (i < 256) {
        acc[0] += w * w_lfa2[i * 4 + 0]; acc[1] += w * w_lfa2[i * 4 + 1];
        acc[2] += w * w_lfa2[i * 4 + 2]; acc[3] += w * w_lfa2[i * 4 + 3];
        acc[8] += w * b_lfa2[i];
      } else if (i < 384) {
        int q = i - 256;
        acc[4] += w * w_lfa1[q * 4 + 0]; acc[5] += w * w_lfa1[q * 4 + 1];
        acc[6] += w * w_lfa1[q * 4 + 2]; acc[7] += w * w_lfa1[q * 4 + 3];
        acc[8] += w * b_lfa1[q];
      } else {
        acc[8] += w * b_mlp1[i - 384];
      }
    }
#pragma unroll
    for (int u = 0; u < 9; ++u) {
      double v = acc[u];
#pragma unroll
      for (int o = 32; o > 0; o >>= 1) v += __shfl_down(v, o, 64);
      if (lane == 0) {
        if (u == 8) v += (double)b_mlp2[j] + (double)b_res[j];
        zbuf[u * D + j] = (float)v;
      }
    }
  }
  {  // Mt[a*D+b] = sum_{i<128} w_mlp2[b][384+i]*w_mlp1[i][a]
    int a = t & 511, b = t >> 9;
    const float* wrow = w_mlp2 + (size_t)b * D + 384;
    double s0 = 0.0, s1 = 0.0, s2 = 0.0, s3 = 0.0;
#pragma unroll 8
    for (int i = 0; i < 128; i += 4) {
      s0 += (double)wrow[i + 0] * (double)w_mlp1[(size_t)(i + 0) * D + a];
      s1 += (double)wrow[i + 1] * (double)w_mlp1[(size_t)(i + 1) * D + a];
      s2 += (double)wrow[i + 2] * (double)w_mlp1[(size_t)(i + 2) * D + a];
      s3 += (double)wrow[i + 3] * (double)w_mlp1[(size_t)(i + 3) * D + a];
    }
    Mt[(size_t)a * D + b] = (float)((s0 + s1) + (s2 + s3));
  }
  {  // Rm[i*D+j] = w_res[j][i] + (i==j)
    int i = t & 511, j = t >> 9;
    Rm[(size_t)i * D + j] = w_res[(size_t)j * D + i] + ((i == j) ? 1.0f : 0.0f);
  }
}

// ---- L1: 14 words (42 blocks: word x c-triple) | s2 2-hop (64) | s1 (16) --
__global__ __launch_bounds__(1024) void stage1_kernel(
    const int* __restrict__ raw, const float* __restrict__ zbuf,
    const float* __restrict__ Mt, const float* __restrict__ Rm,
    float4* __restrict__ sbase, float* __restrict__ wbuf) {
  const bool is64 = knn_is64(raw);
  const int tid = threadIdx.x;
  if (blockIdx.x < 42) {
    // word block: wi = word, rows c = ct..ct+2; z*(B1*B2*...*Bd), fp32
    // intermediates, fp64 accumulate (matches verified chain numerics)
    __shared__ float vin[3][512];
    __shared__ double pr[3][1024];
    int wi = blockIdx.x / 3, ct = (blockIdx.x % 3) * 3;
    int j = tid & 511, half = tid >> 9, k0 = half * 256;
    if (tid < 512) {
#pragma unroll
      for (int cc = 0; cc < 3; ++cc)
        vin[cc][tid] = zbuf[(ct + cc) * D + tid];
    }
    __syncthreads();
    int len = g_wlen[wi];
    for (int st = 0; st < len; ++st) {
      const float* B = g_wseq[wi][st] ? Rm : Mt;
      double a0[3] = {0, 0, 0}, a1[3] = {0, 0, 0};
      for (int kk = 0; kk < 256; kk += 2) {
        float b0 = B[(size_t)(k0 + kk) * D + j];
        float b1 = B[(size_t)(k0 + kk + 1) * D + j];
#pragma unroll
        for (int cc = 0; cc < 3; ++cc) {
          a0[cc] += (double)vin[cc][k0 + kk] * (double)b0;
          a1[cc] += (double)vin[cc][k0 + kk + 1] * (double)b1;
        }
      }
#pragma unroll
      for (int cc = 0; cc < 3; ++cc) pr[cc][tid] = a0[cc] + a1[cc];
      __syncthreads();
      if (tid < 512) {
#pragma unroll
        for (int cc = 0; cc < 3; ++cc)
          vin[cc][tid] = (float)(pr[cc][tid] + pr[cc][tid + 512]);
      }
      __syncthreads();
    }
    if (tid < 512) {
#pragma unroll
      for (int cc = 0; cc < 3; ++cc)
        wbuf[wi * 4608 + (ct + cc) * D + tid] = vin[cc][tid];
    }
  } else if (blockIdx.x < 106) {
    int r = (blockIdx.x - 42) * 1024 + tid;  // 65536 = 4/pt
    twohop(r, raw, is64, sbase, sbase + (size_t)2 * NPTS);
  } else {
    int n = (blockIdx.x - 106) * 1024 + tid;  // 16384
    onehop(n, raw, is64, sbase, sbase + (size_t)1 * NPTS);
  }
}

// ---- L2: s4 2-hop (64) | s3 1-hop (16) | combine -> Ecat (17) ----
__global__ __launch_bounds__(1024) void stage2_kernel(
    const int* __restrict__ raw, float4* __restrict__ sbase,
    const float* __restrict__ zbuf, const float* __restrict__ wbuf,
    float* __restrict__ Ecat) {
  const bool is64 = knn_is64(raw);
  const int tid = threadIdx.x;
  if (blockIdx.x < 64) {
    int r = blockIdx.x * 1024 + tid;
    twohop(r, raw, is64, sbase + (size_t)2 * NPTS, sbase + (size_t)4 * NPTS);
  } else if (blockIdx.x < 80) {
    int n = (blockIdx.x - 64) * 1024 + tid;
    onehop(n, raw, is64, sbase + (size_t)2 * NPTS, sbase + (size_t)3 * NPTS);
  } else {
    int rel = (blockIdx.x - 80) * 1024 + tid;
    if (rel < 33 * 512) {
      int r = rel >> 9, j = rel & 511;
      float s = 0.f;
      if (r < 32) {
        int ci = r >> 3, c = r & 7;
        if (ci == 0) s += zbuf[c * D + j];
#pragma unroll
        for (int u = 0; u < 6; ++u) {
          int w = g_wgroups[ci][u];
          if (w >= 0) s += wbuf[w * 4608 + c * D + j];
        }
      } else {
        s = zbuf[8 * D + j];
#pragma unroll
        for (int w = 0; w < 14; ++w) s += wbuf[w * 4608 + 8 * D + j];
      }
      Ecat[r * D + j] = s;
    }
  }
}

// ---- L3: s6 2-hop (64) | s5 1-hop (16) ----
__global__ __launch_bounds__(1024) void stage3_kernel(
    const int* __restrict__ raw, float4* __restrict__ sbase) {
  const bool is64 = knn_is64(raw);
  const int tid = threadIdx.x;
  if (blockIdx.x < 64) {
    int r = blockIdx.x * 1024 + tid;
    twohop(r, raw, is64, sbase + (size_t)4 * NPTS, sbase + (size_t)6 * NPTS);
  } else {
    int n = (blockIdx.x - 64) * 1024 + tid;
    onehop(n, raw, is64, sbase + (size_t)4 * NPTS, sbase + (size_t)5 * NPTS);
  }
}

// ---- L4: out[n][:] = [s0..s7,1][n] x Ecat; s7 computed inline per block ----
// 256 blocks x 1024 thr; block handles 64 points x all 512 cols.
__global__ __launch_bounds__(1024, 4) void out_kernel(
    const int* __restrict__ raw, const float4* __restrict__ sbase,
    const float* __restrict__ Ecat, float* __restrict__ outp) {
  const bool is64 = knn_is64(raw);
  const int tid = threadIdx.x;
  const int n0 = blockIdx.x * 64;
  __shared__ float4 s_t[8][64];
  {  // s7 for this block's points: 16 threads/point, shfl-reduce
    int pt = tid >> 4, k = tid & 15;
    int n = n0 + pt;
    float4 g = sbase[(size_t)6 * NPTS + knn_at(raw, is64, n * KNB + k)];
    float ax = g.x, ay = g.y, az = g.z, aw = g.w;
#pragma unroll
    for (int o = 1; o < 16; o <<= 1) {
      ax += __shfl_xor(ax, o, 64); ay += __shfl_xor(ay, o, 64);
      az += __shfl_xor(az, o, 64); aw += __shfl_xor(aw, o, 64);
    }
    if (k == 0) {
      const float r = 1.f / 16.f;
      s_t[7][pt] = make_float4(ax * r, ay * r, az * r, aw * r);
    }
  }
  if (tid < 448) {  // load s0..s6 tiles
    int k = tid / 64, pt = tid & 63;
    s_t[k][pt] = sbase[(size_t)k * NPTS + n0 + pt];
  }
  __syncthreads();
  // register-hoisted Ecat column pair
  const int col2 = tid & 255;   // float2 column
  const int ptg = tid >> 8;     // 0..3
  float2 tab[33];
#pragma unroll
  for (int r = 0; r < 33; ++r)
    tab[r] = *(const float2*)(Ecat + r * D + col2 * 2);
#pragma unroll
  for (int it = 0; it < 16; ++it) {
    int pt = ptg * 16 + it;
    float2 acc = tab[32];
#pragma unroll
    for (int k = 0; k < 8; ++k) {
      float4 s = s_t[k][pt];  // wave-uniform LDS broadcast
      float2 e0 = tab[4 * k + 0], e1 = tab[4 * k + 1];
      float2 e2 = tab[4 * k + 2], e3 = tab[4 * k + 3];
      acc.x += s.x * e0.x + s.y * e1.x + s.z * e2.x + s.w * e3.x;
      acc.y += s.x * e0.y + s.y * e1.y + s.z * e2.y + s.w * e3.y;
    }
    *(float2*)(outp + (size_t)(n0 + pt) * D + col2 * 2) = acc;
  }
}

extern "C" void kernel_launch(void* const* d_in, const int* in_sizes, int n_in,
                              void* d_out, int out_size, void* d_ws,
                              size_t ws_size, hipStream_t stream) {
  const float* inputs = (const float*)d_in[0];
  const int* knn_raw  = (const int*)d_in[1];
  const float* w_mlp1 = (const float*)d_in[2];
  const float* b_mlp1 = (const float*)d_in[3];
  const float* w_lfa1 = (const float*)d_in[4];
  const float* b_lfa1 = (const float*)d_in[5];
  const float* w_lfa2 = (const float*)d_in[6];
  const float* b_lfa2 = (const float*)d_in[7];
  const float* w_mlp2 = (const float*)d_in[8];
  const float* b_mlp2 = (const float*)d_in[9];
  const float* w_res  = (const float*)d_in[10];
  const float* b_res  = (const float*)d_in[11];
  float* out = (float*)d_out;

  // workspace (floats): ~4.6 MB
  float*  ws    = (float*)d_ws;
  float4* sbase = (float4*)(ws + 0);   // 8 * 16384 float4
  float*  zbuf  = ws + 524288;         // 9 * 512
  float*  wbuf  = ws + 528896;         // 14 * 9 * 512
  float*  Ecat  = ws + 593408;         // 33 * 512
  float*  Mt    = ws + 610304;         // 512*512
  float*  Rm    = ws + 872448;         // 512*512

  prep_kernel<<<1024, 256, 0, stream>>>(inputs, knn_raw, w_mlp1, b_mlp1,
                                        w_lfa1, b_lfa1, w_lfa2, b_lfa2,
                                        w_mlp2, b_mlp2, w_res, b_res,
                                        sbase, zbuf, Mt, Rm);
  stage1_kernel<<<122, 1024, 0, stream>>>(knn_raw, zbuf, Mt, Rm, sbase, wbuf);
  stage2_kernel<<<97, 1024, 0, stream>>>(knn_raw, sbase, zbuf, wbuf, Ecat);
  stage3_kernel<<<80, 1024, 0, stream>>>(knn_raw, sbase);
  out_kernel<<<256, 1024, 0, stream>>>(knn_raw, sbase, Ecat, out);
}

// Round 7
// 201.603 us; speedup vs baseline: 2.9132x; 1.4279x over previous
//
#include <hip/hip_runtime.h>
#include <math.h>

#define NPTS 16384
#define KNB  16
#define D    512

// ---------------------------------------------------------------------------
// Closed-form restructure (verified rounds 1-6, absmax 0.0625). With
// S = gather-mean, R = Wres^T + I, M' = (W2c*W1)^T, and the per-block map
// f' = Cb + S^2 f M' + f R (f0 = 0), track F_t in [33,512] coefficient space
// (rows 4k+c = component c of s_k, row 32 = bias):
//   F_1 = Cb33,   F_{t+1} = Cb33 + Shift2(F_t)*M' + F_t*R,   Ecat = F_4
// where Shift2 moves row-block k -> k+2 (bias row -> itself, S row-stochastic)
// and Cb33 rows {0..7} = z rows {0..7}, row 32 = z row 8 (z = [P|Q|btot]^T).
// Final: out = [s0..s7,1] ([N,33]) x Ecat.
// Round 7: fat gathers (16 threads/point, shfl reduce) fix round-6's
// latency-starved hops; Horner F-recursion replaces the 14-word recompute.
// ---------------------------------------------------------------------------

__device__ __forceinline__ float4 red16(float ax, float ay, float az,
                                        float aw) {
#pragma unroll
  for (int o = 1; o < 16; o <<= 1) {
    ax += __shfl_xor(ax, o, 64); ay += __shfl_xor(ay, o, 64);
    az += __shfl_xor(az, o, 64); aw += __shfl_xor(aw, o, 64);
  }
  return make_float4(ax, ay, az, aw);
}

// 1-hop gather-mean, 16 threads/point (t < 262144)
__device__ __forceinline__ void onehop16(int t, const int* __restrict__ knn,
                                         const float4* __restrict__ in,
                                         float4* __restrict__ out) {
  int n = t >> 4, k = t & 15;
  float4 g = in[knn[n * KNB + k]];
  float4 s = red16(g.x, g.y, g.z, g.w);
  if (k == 0) {
    const float r = 1.f / 16.f;
    out[n] = make_float4(s.x * r, s.y * r, s.z * r, s.w * r);
  }
}

// 2-hop gather-mean, 16 threads/point (one outer neighbor, 16 inner each)
__device__ __forceinline__ void twohop16(int t, const int* __restrict__ knn,
                                         const float4* __restrict__ in,
                                         float4* __restrict__ out) {
  int n = t >> 4, a = t & 15;
  int ia = knn[n * KNB + a];
  const int4* ip = (const int4*)(knn + ia * KNB);  // 64B-aligned
  int4 i0 = ip[0], i1 = ip[1], i2 = ip[2], i3 = ip[3];
  float ax = 0.f, ay = 0.f, az = 0.f, aw = 0.f;
#define ACC(idx) { float4 g = in[idx]; ax += g.x; ay += g.y; az += g.z; aw += g.w; }
  ACC(i0.x) ACC(i0.y) ACC(i0.z) ACC(i0.w)
  ACC(i1.x) ACC(i1.y) ACC(i1.z) ACC(i1.w)
  ACC(i2.x) ACC(i2.y) ACC(i2.z) ACC(i2.w)
  ACC(i3.x) ACC(i3.y) ACC(i3.z) ACC(i3.w)
#undef ACC
  float4 s = red16(ax, ay, az, aw);
  if (a == 0) {
    const float r = 1.f / 256.f;
    out[n] = make_float4(s.x * r, s.y * r, s.z * r, s.w * r);
  }
}

// One Horner step: Fnext[r][j] = cb(r,j) + sum_k Fprev[r][k]R[k][j]
//                               + sum_k Fprev[rm][k]M'[k][j]
// rm = r-8 (rows 8..31), 32 for bias row, none for rows 0..7.
// rb in [0,132): r = rb>>2, col-chunk = rb&3. 1024 thr: 128 cols x 8 k-chunks.
__device__ __forceinline__ void fstep_block(
    int rb, int tid, int first, const float* __restrict__ Fprev,
    const float* __restrict__ zbuf, const double* __restrict__ Rmd,
    const double* __restrict__ Mtd, float* __restrict__ Fnext) {
  __shared__ double sA[512], sB[512];
  __shared__ double red[8][128];
  const int r = rb >> 2, cchunk = rb & 3;
  const int rm = (r >= 8 && r < 32) ? (r - 8) : (r == 32 ? 32 : -1);
  if (tid < 512) {
    float v;
    if (first)
      v = (r < 8) ? zbuf[r * D + tid] : (r == 32 ? zbuf[8 * D + tid] : 0.f);
    else
      v = Fprev[r * D + tid];
    sA[tid] = (double)v;
  } else {
    int kk = tid - 512;
    float v = 0.f;
    if (rm >= 0) {
      if (first)
        v = (rm < 8) ? zbuf[rm * D + kk] : (rm == 32 ? zbuf[8 * D + kk] : 0.f);
      else
        v = Fprev[rm * D + kk];
    }
    sB[kk] = (double)v;
  }
  __syncthreads();
  const int col = tid & 127, kc = tid >> 7;
  const int j = cchunk * 128 + col, k0 = kc * 64;
  double a0 = 0.0, a1 = 0.0;
  for (int k = 0; k < 64; k += 2) {
    a0 += sA[k0 + k] * Rmd[(size_t)(k0 + k) * D + j] +
          sB[k0 + k] * Mtd[(size_t)(k0 + k) * D + j];
    a1 += sA[k0 + k + 1] * Rmd[(size_t)(k0 + k + 1) * D + j] +
          sB[k0 + k + 1] * Mtd[(size_t)(k0 + k + 1) * D + j];
  }
  red[kc][col] = a0 + a1;
  __syncthreads();
  if (kc == 0) {
    double s = 0.0;
#pragma unroll
    for (int u = 0; u < 8; ++u) s += red[u][col];
    float cb = (r < 8) ? zbuf[r * D + j] : (r == 32 ? zbuf[8 * D + j] : 0.f);
    Fnext[r * D + j] = (float)(s + (double)cb);
  }
}

// ---- L0: knn normalize | geo (16 thr/pt) | pq(z) | Mtd | Rmd ----
__global__ __launch_bounds__(256) void prep_kernel(
    const float* __restrict__ pts, const int* __restrict__ raw,
    const float* __restrict__ w_mlp1, const float* __restrict__ b_mlp1,
    const float* __restrict__ w_lfa1, const float* __restrict__ b_lfa1,
    const float* __restrict__ w_lfa2, const float* __restrict__ b_lfa2,
    const float* __restrict__ w_mlp2, const float* __restrict__ b_mlp2,
    const float* __restrict__ w_res, const float* __restrict__ b_res,
    int* __restrict__ knn_i, float4* __restrict__ sbase,
    float* __restrict__ zbuf, double* __restrict__ Mtd,
    double* __restrict__ Rmd) {
  // int64 little-endian => odd words are zero high halves; (1/16384)^4 FP risk
  const bool is64 = (raw[1] == 0) && (raw[3] == 0) && (raw[5] == 0) &&
                    (raw[7] == 0);
  const int t = blockIdx.x * 256 + threadIdx.x;  // < 262144 == D*D
  knn_i[t] = is64 ? raw[2 * t] : raw[t];
  {  // geo: 16 threads/point
    int n = t >> 4, k = t & 15;
    int idx = is64 ? raw[2 * (n * KNB + k)] : raw[n * KNB + k];
    float dx = pts[n * 3 + 0] - pts[idx * 3 + 0];
    float dy = pts[n * 3 + 1] - pts[idx * 3 + 1];
    float dz = pts[n * 3 + 2] - pts[idx * 3 + 2];
    float nr = sqrtf(dx * dx + dy * dy + dz * dz);
    float4 s = red16(dx, dy, dz, nr);
    if (k == 0) {
      const float r = 1.f / 16.f;
      sbase[n] = make_float4(s.x * r, s.y * r, s.z * r, s.w * r);
    }
  }
  if (t < 32768) {  // pq: one wave per output column j; fp64 accumulate
    int j = t >> 6, lane = t & 63;
    const float* wrow = w_mlp2 + (size_t)j * D;
    double acc[9];
#pragma unroll
    for (int u = 0; u < 9; ++u) acc[u] = 0.0;
#pragma unroll
    for (int it = 0; it < 8; ++it) {
      int i = lane + 64 * it;
      double w = wrow[i];
      if (i < 256) {
        acc[0] += w * w_lfa2[i * 4 + 0]; acc[1] += w * w_lfa2[i * 4 + 1];
        acc[2] += w * w_lfa2[i * 4 + 2]; acc[3] += w * w_lfa2[i * 4 + 3];
        acc[8] += w * b_lfa2[i];
      } else if (i < 384) {
        int q = i - 256;
        acc[4] += w * w_lfa1[q * 4 + 0]; acc[5] += w * w_lfa1[q * 4 + 1];
        acc[6] += w * w_lfa1[q * 4 + 2]; acc[7] += w * w_lfa1[q * 4 + 3];
        acc[8] += w * b_lfa1[q];
      } else {
        acc[8] += w * b_mlp1[i - 384];
      }
    }
#pragma unroll
    for (int u = 0; u < 9; ++u) {
      double v = acc[u];
#pragma unroll
      for (int o = 32; o > 0; o >>= 1) v += __shfl_down(v, o, 64);
      if (lane == 0) {
        if (u == 8) v += (double)b_mlp2[j] + (double)b_res[j];
        zbuf[u * D + j] = (float)v;
      }
    }
  }
  {  // Mtd[a*D+b] = sum_{i<128} w_mlp2[b][384+i]*w_mlp1[i][a]  (fp64)
    int a = t & 511, b = t >> 9;
    const float* wrow = w_mlp2 + (size_t)b * D + 384;
    double s0 = 0.0, s1 = 0.0, s2 = 0.0, s3 = 0.0;
#pragma unroll 8
    for (int i = 0; i < 128; i += 4) {
      s0 += (double)wrow[i + 0] * (double)w_mlp1[(size_t)(i + 0) * D + a];
      s1 += (double)wrow[i + 1] * (double)w_mlp1[(size_t)(i + 1) * D + a];
      s2 += (double)wrow[i + 2] * (double)w_mlp1[(size_t)(i + 2) * D + a];
      s3 += (double)wrow[i + 3] * (double)w_mlp1[(size_t)(i + 3) * D + a];
    }
    Mtd[(size_t)a * D + b] = (s0 + s1) + (s2 + s3);
  }
  {  // Rmd[i*D+j] = w_res[j][i] + (i==j)
    int i = t & 511, j = t >> 9;
    Rmd[(size_t)i * D + j] =
        (double)w_res[(size_t)j * D + i] + ((i == j) ? 1.0 : 0.0);
  }
}

// ---- L1..L3: fstep (132 blocks) | 2-hop (256) | 1-hop (256) ----
__global__ __launch_bounds__(1024) void stage_kernel(
    const int* __restrict__ knn, const float* __restrict__ zbuf,
    const double* __restrict__ Rmd, const double* __restrict__ Mtd,
    const float* __restrict__ Fprev, float* __restrict__ Fnext, int first,
    const float4* __restrict__ sin, float4* __restrict__ sout1,
    float4* __restrict__ sout2) {
  const int tid = threadIdx.x;
  if (blockIdx.x < 132) {
    fstep_block(blockIdx.x, tid, first, Fprev, zbuf, Rmd, Mtd, Fnext);
  } else if (blockIdx.x < 388) {
    twohop16((blockIdx.x - 132) * 1024 + tid, knn, sin, sout2);
  } else {
    onehop16((blockIdx.x - 388) * 1024 + tid, knn, sin, sout1);
  }
}

// ---- L4: out[n][:] = [s0..s7,1][n] x Ecat; s7 inline (1-hop from s6) ----
__global__ __launch_bounds__(1024, 4) void out_kernel(
    const int* __restrict__ knn, const float4* __restrict__ sbase,
    const float* __restrict__ Ecat, float* __restrict__ outp) {
  const int tid = threadIdx.x;
  const int n0 = blockIdx.x * 64;
  __shared__ float4 s_t[8][64];
  {  // s7 for this block's 64 points: 16 threads/point
    int pt = tid >> 4, k = tid & 15;
    float4 g = sbase[(size_t)6 * NPTS + knn[(n0 + pt) * KNB + k]];
    float4 s = red16(g.x, g.y, g.z, g.w);
    if (k == 0) {
      const float r = 1.f / 16.f;
      s_t[7][pt] = make_float4(s.x * r, s.y * r, s.z * r, s.w * r);
    }
  }
  if (tid < 448) {  // load s0..s6 tiles
    int k = tid / 64, pt = tid & 63;
    s_t[k][pt] = sbase[(size_t)k * NPTS + n0 + pt];
  }
  __syncthreads();
  const int col2 = tid & 255;  // this thread's float2 column
  const int ptg = tid >> 8;    // 0..3
  float2 tab[33];
#pragma unroll
  for (int r = 0; r < 33; ++r)
    tab[r] = *(const float2*)(Ecat + r * D + col2 * 2);
#pragma unroll
  for (int it = 0; it < 16; ++it) {
    int pt = ptg * 16 + it;
    float2 acc = tab[32];
#pragma unroll
    for (int k = 0; k < 8; ++k) {
      float4 s = s_t[k][pt];  // wave-uniform LDS broadcast
      float2 e0 = tab[4 * k + 0], e1 = tab[4 * k + 1];
      float2 e2 = tab[4 * k + 2], e3 = tab[4 * k + 3];
      acc.x += s.x * e0.x + s.y * e1.x + s.z * e2.x + s.w * e3.x;
      acc.y += s.x * e0.y + s.y * e1.y + s.z * e2.y + s.w * e3.y;
    }
    *(float2*)(outp + (size_t)(n0 + pt) * D + col2 * 2) = acc;
  }
}

extern "C" void kernel_launch(void* const* d_in, const int* in_sizes, int n_in,
                              void* d_out, int out_size, void* d_ws,
                              size_t ws_size, hipStream_t stream) {
  const float* inputs = (const float*)d_in[0];
  const int* knn_raw  = (const int*)d_in[1];
  const float* w_mlp1 = (const float*)d_in[2];
  const float* b_mlp1 = (const float*)d_in[3];
  const float* w_lfa1 = (const float*)d_in[4];
  const float* b_lfa1 = (const float*)d_in[5];
  const float* w_lfa2 = (const float*)d_in[6];
  const float* b_lfa2 = (const float*)d_in[7];
  const float* w_mlp2 = (const float*)d_in[8];
  const float* b_mlp2 = (const float*)d_in[9];
  const float* w_res  = (const float*)d_in[10];
  const float* b_res  = (const float*)d_in[11];
  float* out = (float*)d_out;

  // workspace (floats): ~7.6 MB
  float*  ws    = (float*)d_ws;
  float4* sbase = (float4*)(ws + 0);          // 8 * 16384 float4
  float*  zbuf  = ws + 524288;                // 9 * 512
  float*  F2    = ws + 528896;                // 33 * 512
  float*  F3    = ws + 545792;                // 33 * 512
  float*  Ecat  = ws + 562688;                // 33 * 512
  int*    knn_i = (int*)(ws + 579584);        // 262144 ints
  double* Mtd   = (double*)(ws + 841728);     // 262144 doubles (8B-aligned)
  double* Rmd   = (double*)(ws + 1366016);    // 262144 doubles

  prep_kernel<<<1024, 256, 0, stream>>>(inputs, knn_raw, w_mlp1, b_mlp1,
                                        w_lfa1, b_lfa1, w_lfa2, b_lfa2,
                                        w_mlp2, b_mlp2, w_res, b_res,
                                        knn_i, sbase, zbuf, Mtd, Rmd);
  // L1: F2 = step(F1=Cb) | s2 = S^2 s0 | s1 = S s0
  stage_kernel<<<644, 1024, 0, stream>>>(
      knn_i, zbuf, Rmd, Mtd, (const float*)nullptr, F2, 1, sbase,
      sbase + (size_t)1 * NPTS, sbase + (size_t)2 * NPTS);
  // L2: F3 = step(F2) | s4 = S^2 s2 | s3 = S s2
  stage_kernel<<<644, 1024, 0, stream>>>(
      knn_i, zbuf, Rmd, Mtd, F2, F3, 0, sbase + (size_t)2 * NPTS,
      sbase + (size_t)3 * NPTS, sbase + (size_t)4 * NPTS);
  // L3: Ecat = F4 = step(F3) | s6 = S^2 s4 | s5 = S s4
  stage_kernel<<<644, 1024, 0, stream>>>(
      knn_i, zbuf, Rmd, Mtd, F3, Ecat, 0, sbase + (size_t)4 * NPTS,
      sbase + (size_t)5 * NPTS, sbase + (size_t)6 * NPTS);
  // L4: out (s7 inline)
  out_kernel<<<256, 1024, 0, stream>>>(knn_i, sbase, Ecat, out);
}